// Round 12
// baseline (311.843 us; speedup 1.0000x reference)
//
#include <hip/hip_runtime.h>
#include <hip/hip_bf16.h>

// Problem constants (fixed by the reference harness)
#define NN 65536            // total nodes
#define NE (NN * 16)        // total edges = 1,048,576
#define NG 32               // graphs
#define MAXD 64             // ELL slots per node (max in-degree ~45 for Poisson(16))

// Workspace layout (bytes).  z/h buffers are bf16 (2B), z4 is f32.
#define WS_CURSOR 0                         // NN ints   = 256 KB
#define WS_SUMMED 262144                    // NG*30 f32
#define WS_ELL    1048576                   // int ELL: NN*64*4 = 16 MB
#define WS_ZA     (WS_ELL + NN * MAXD * 4)  // NN*32 bf16 = 4 MB
#define WS_ZB     (WS_ZA + NN * 32 * 2)
#define WS_H1     (WS_ZB + NN * 32 * 2)
#define WS_H2     (WS_H1 + NN * 32 * 2)
#define WS_H3     (WS_H2 + NN * 32 * 2)
#define WS_Z4     (WS_H3 + NN * 32 * 2)     // NN f32

typedef unsigned short bf16;

// XCD-affine swizzle: 8 XCDs, round-robin dispatch (blockIdx % 8).
__device__ __forceinline__ int xcd_swz(int b, int chunk) {
    return (b & 7) * chunk + (b >> 3);
}

__device__ __forceinline__ float ftanh(float x) {
    float xc = fmaxf(fminf(x, 15.f), -15.f);
    float e = __expf(2.f * xc);
    return (e - 1.f) * __builtin_amdgcn_rcpf(e + 1.f);
}

__device__ __forceinline__ float bf2f(bf16 u) {
    return __uint_as_float(((unsigned int)u) << 16);
}
__device__ __forceinline__ bf16 f2bf(float x) {
    unsigned int b = __float_as_uint(x);
    b += 0x7FFF + ((b >> 16) & 1);          // round to nearest even
    return (bf16)(b >> 16);
}

// ---------------------------------------------------------------------------
// Build int ELL: ell[dst*64+slot] = src.  Proven round-3 shape (~56 us).
__global__ __launch_bounds__(256) void k_build(const int* __restrict__ ei,
                                               int* __restrict__ cursor,
                                               int* __restrict__ ell) {
    int blk = xcd_swz(blockIdx.x, 128);             // 1024 blocks -> chunk 128
    int idx = blk * 256 + threadIdx.x;
    const int4* e4 = (const int4*)ei;
    int4 s = e4[idx];
    int4 d = e4[NE / 4 + idx];
    int t;
    t = atomicAdd(&cursor[d.x], 1); if (t < MAXD) ell[d.x * MAXD + t] = s.x;
    t = atomicAdd(&cursor[d.y], 1); if (t < MAXD) ell[d.y * MAXD + t] = s.y;
    t = atomicAdd(&cursor[d.z], 1); if (t < MAXD) ell[d.z * MAXD + t] = s.z;
    t = atomicAdd(&cursor[d.w], 1); if (t < MAXD) ell[d.w * MAXD + t] = s.w;
}

// ---------------------------------------------------------------------------
// z1 = feat (N x 128) @ W0 (128 x 32), output bf16.
__global__ __launch_bounds__(256) void k_gemm1(const float* __restrict__ feat,
                                               const float* __restrict__ W0,
                                               bf16* __restrict__ z1) {
    __shared__ float wl[32 * 132];
    __shared__ float hl[64 * 132];
    int tid = threadIdx.x;
    for (int i = tid; i < 128 * 32; i += 256) {
        int k = i >> 5, c = i & 31;
        wl[c * 132 + k] = W0[i];
    }
    int base = blockIdx.x * 64;
    const float* fsrc = feat + (size_t)base * 128;
    #pragma unroll
    for (int v = 0; v < 8; ++v) {
        int flat = v * 1024 + tid * 4;
        int rr = flat >> 7, kk = flat & 127;
        *(float4*)&hl[rr * 132 + kk] = *(const float4*)&fsrc[flat];
    }
    __syncthreads();
    int cg = tid & 15, rg = tid >> 4;
    int c0 = cg * 2, r0 = rg * 4;
    float acc[4][2] = {};
    #pragma unroll 2
    for (int k = 0; k < 128; k += 4) {
        float4 wa = *(const float4*)&wl[c0 * 132 + k];
        float4 wb = *(const float4*)&wl[(c0 + 1) * 132 + k];
        #pragma unroll
        for (int rr = 0; rr < 4; ++rr) {
            float4 hv = *(const float4*)&hl[(r0 + rr) * 132 + k];
            acc[rr][0] += hv.x * wa.x + hv.y * wa.y + hv.z * wa.z + hv.w * wa.w;
            acc[rr][1] += hv.x * wb.x + hv.y * wb.y + hv.z * wb.z + hv.w * wb.w;
        }
    }
    #pragma unroll
    for (int rr = 0; rr < 4; ++rr) {
        int d = base + r0 + rr;
        unsigned int pk = (unsigned int)f2bf(acc[rr][0]) |
                          ((unsigned int)f2bf(acc[rr][1]) << 16);
        *(unsigned int*)&z1[(size_t)d * 32 + c0] = pk;
    }
}

// ---------------------------------------------------------------------------
// LDS gather: zl holds the full graph slice (2048 rows x 32 bf16).
// 8-lane node group; lane q handles cols 4q..4q+3; indices masked in-graph.
#define GB8L(iv) do {                                                          \
    int s0=__shfl((iv),0,8)&2047, s1=__shfl((iv),1,8)&2047;                    \
    int s2=__shfl((iv),2,8)&2047, s3=__shfl((iv),3,8)&2047;                    \
    int s4=__shfl((iv),4,8)&2047, s5=__shfl((iv),5,8)&2047;                    \
    int s6=__shfl((iv),6,8)&2047, s7=__shfl((iv),7,8)&2047;                    \
    ushort4 v0=*(const ushort4*)&zl[s0*32+q4];                                 \
    ushort4 v1=*(const ushort4*)&zl[s1*32+q4];                                 \
    ushort4 v2=*(const ushort4*)&zl[s2*32+q4];                                 \
    ushort4 v3=*(const ushort4*)&zl[s3*32+q4];                                 \
    ushort4 v4=*(const ushort4*)&zl[s4*32+q4];                                 \
    ushort4 v5=*(const ushort4*)&zl[s5*32+q4];                                 \
    ushort4 v6=*(const ushort4*)&zl[s6*32+q4];                                 \
    ushort4 v7=*(const ushort4*)&zl[s7*32+q4];                                 \
    acc.x += ((bf2f(v0.x)+bf2f(v1.x))+(bf2f(v2.x)+bf2f(v3.x)))                 \
           + ((bf2f(v4.x)+bf2f(v5.x))+(bf2f(v6.x)+bf2f(v7.x)));                \
    acc.y += ((bf2f(v0.y)+bf2f(v1.y))+(bf2f(v2.y)+bf2f(v3.y)))                 \
           + ((bf2f(v4.y)+bf2f(v5.y))+(bf2f(v6.y)+bf2f(v7.y)));                \
    acc.z += ((bf2f(v0.z)+bf2f(v1.z))+(bf2f(v2.z)+bf2f(v3.z)))                 \
           + ((bf2f(v4.z)+bf2f(v5.z))+(bf2f(v6.z)+bf2f(v7.z)));                \
    acc.w += ((bf2f(v0.w)+bf2f(v1.w))+(bf2f(v2.w)+bf2f(v3.w)))                 \
           + ((bf2f(v4.w)+bf2f(v5.w))+(bf2f(v6.w)+bf2f(v7.w)));                \
} while (0)

__device__ __forceinline__ float4 gatherlds(const int* __restrict__ row, int cnt,
                                            const bf16* zl, int q4, float4 acc) {
    int q = q4 >> 2;
    int i0 = row[q], i1 = row[8 + q], i2 = row[16 + q], i3 = row[24 + q];
    int m = cnt < 32 ? cnt : 32;
    if (m >= 8)  GB8L(i0);
    if (m >= 16) GB8L(i1);
    if (m >= 24) GB8L(i2);
    if (m >= 32) GB8L(i3);
    int done = m & ~7;
    if (done < m) {
        int ivr = (done == 0) ? i0 : (done == 8) ? i1 : (done == 16) ? i2 : i3;
        for (int j = done; j < m; ++j) {
            int s = __shfl(ivr, j - done, 8) & 2047;
            ushort4 v = *(const ushort4*)&zl[s * 32 + q4];
            acc.x += bf2f(v.x); acc.y += bf2f(v.y);
            acc.z += bf2f(v.z); acc.w += bf2f(v.w);
        }
    }
    for (int j = 32; j < cnt && j < MAXD; ++j) {     // astronomically rare
        int s = row[j] & 2047;
        ushort4 v = *(const ushort4*)&zl[s * 32 + q4];
        acc.x += bf2f(v.x); acc.y += bf2f(v.y);
        acc.z += bf2f(v.z); acc.w += bf2f(v.w);
    }
    return acc;
}

// ---------------------------------------------------------------------------
// LDS-staged layer: block = 256 nodes of one graph; whole graph z-slice
// (128 KB) staged in LDS; gathers hit LDS only.  zl region reused for the
// matvec h-tile + weight tile after the gather barrier (static LDS = 128 KiB).
__global__ __launch_bounds__(1024) void k_layer(const float* __restrict__ degs,
                                                const int* __restrict__ ell,
                                                const bf16* __restrict__ zin,
                                                const float* __restrict__ bias,
                                                const float* __restrict__ Wn,
                                                bf16* __restrict__ hout,
                                                bf16* __restrict__ znext) {
    __shared__ __align__(16) unsigned char smem[131072];   // 128 KiB
    bf16*  zl = (bf16*)smem;                 // [2048][32] during gather
    float* hl = (float*)smem;                // [256][36] after reuse
    float* wt = (float*)(smem + 256 * 36 * 4);   // [32][36] after reuse
    int tid = threadIdx.x;
    int blk = xcd_swz(blockIdx.x, 32);       // 256 blocks -> graph g on one XCD
    int g = blk >> 3;
    int nbase = (blk & 7) << 8;              // node offset within graph
    const bf16* zg = zin + (((size_t)g << 11) << 5);
    {   // stage 128 KB, coalesced
        const uint4* src = (const uint4*)zg;
        uint4* dst = (uint4*)smem;
        #pragma unroll
        for (int i = 0; i < 8; ++i) dst[tid + i * 1024] = src[tid + i * 1024];
    }
    __syncthreads();

    int grp = tid >> 3, q4 = (tid & 7) * 4;
    float4 val[2];
    #pragma unroll
    for (int it = 0; it < 2; ++it) {
        int rr = grp + it * 128;             // 0..255
        int dl = nbase + rr;                 // in-graph node index
        int d  = (g << 11) + dl;             // global node index
        float degv = degs[d];
        int cnt = (int)degv - 1;
        const int* row = ell + (size_t)d * MAXD;
        ushort4 sv = *(const ushort4*)&zl[dl * 32 + q4];     // self term (LDS)
        float4 acc = {bf2f(sv.x), bf2f(sv.y), bf2f(sv.z), bf2f(sv.w)};
        acc = gatherlds(row, cnt, zl, q4, acc);
        float4 b4 = *(const float4*)&bias[q4];
        float rdeg = __builtin_amdgcn_rcpf(degv);
        val[it].x = ftanh((acc.x + b4.x) * rdeg);
        val[it].y = ftanh((acc.y + b4.y) * rdeg);
        val[it].z = ftanh((acc.z + b4.z) * rdeg);
        val[it].w = ftanh((acc.w + b4.w) * rdeg);
        ushort4 hv4 = {f2bf(val[it].x), f2bf(val[it].y),
                       f2bf(val[it].z), f2bf(val[it].w)};
        *(ushort4*)&hout[(size_t)d * 32 + q4] = hv4;
    }
    __syncthreads();                         // gathers done; zl region is dead

    #pragma unroll
    for (int it = 0; it < 2; ++it) {
        int rr = grp + it * 128;
        *(float4*)&hl[rr * 36 + q4] = val[it];
    }
    if (tid < 1024) {                        // wt: one element per thread
        int k = tid >> 5, c = tid & 31;
        wt[c * 36 + k] = Wn[tid];
    }
    __syncthreads();

    // matvec: thread -> node n = tid>>2, cols c0..c0+7 (uint4-packed store)
    int n = tid >> 2, c0 = (tid & 3) * 8;
    const float* hrow = &hl[n * 36];
    float o[8];
    #pragma unroll
    for (int cc = 0; cc < 8; ++cc) {
        const float* wrow = &wt[(c0 + cc) * 36];
        float4 a = {0.f, 0.f, 0.f, 0.f};
        #pragma unroll
        for (int k = 0; k < 32; k += 4) {
            float4 hv = *(const float4*)&hrow[k];
            float4 wv = *(const float4*)&wrow[k];
            a.x += hv.x * wv.x; a.y += hv.y * wv.y;
            a.z += hv.z * wv.z; a.w += hv.w * wv.w;
        }
        o[cc] = (a.x + a.y) + (a.z + a.w);
    }
    int dn = (g << 11) + nbase + n;
    uint4 pk;
    pk.x = (unsigned int)f2bf(o[0]) | ((unsigned int)f2bf(o[1]) << 16);
    pk.y = (unsigned int)f2bf(o[2]) | ((unsigned int)f2bf(o[3]) << 16);
    pk.z = (unsigned int)f2bf(o[4]) | ((unsigned int)f2bf(o[5]) << 16);
    pk.w = (unsigned int)f2bf(o[6]) | ((unsigned int)f2bf(o[7]) << 16);
    *(uint4*)&znext[(size_t)dn * 32 + c0] = pk;
}

// ---------------------------------------------------------------------------
// Layer-3: same LDS-staged gather; epilogue is 1-wide dot (z4 = h3 @ W3, f32).
__global__ __launch_bounds__(1024) void k_layer3(const float* __restrict__ degs,
                                                 const int* __restrict__ ell,
                                                 const bf16* __restrict__ zin,
                                                 const float* __restrict__ bias,
                                                 const float* __restrict__ W3,
                                                 bf16* __restrict__ hout,
                                                 float* __restrict__ z4) {
    __shared__ __align__(16) unsigned char smem[131072];
    bf16* zl = (bf16*)smem;
    int tid = threadIdx.x;
    int blk = xcd_swz(blockIdx.x, 32);
    int g = blk >> 3;
    int nbase = (blk & 7) << 8;
    const bf16* zg = zin + (((size_t)g << 11) << 5);
    {
        const uint4* src = (const uint4*)zg;
        uint4* dst = (uint4*)smem;
        #pragma unroll
        for (int i = 0; i < 8; ++i) dst[tid + i * 1024] = src[tid + i * 1024];
    }
    __syncthreads();

    int grp = tid >> 3, q = tid & 7, q4 = q * 4;
    float4 w4 = *(const float4*)&W3[q4];
    #pragma unroll
    for (int it = 0; it < 2; ++it) {
        int rr = grp + it * 128;
        int dl = nbase + rr;
        int d  = (g << 11) + dl;
        float degv = degs[d];
        int cnt = (int)degv - 1;
        const int* row = ell + (size_t)d * MAXD;
        ushort4 sv = *(const ushort4*)&zl[dl * 32 + q4];
        float4 acc = {bf2f(sv.x), bf2f(sv.y), bf2f(sv.z), bf2f(sv.w)};
        acc = gatherlds(row, cnt, zl, q4, acc);
        float4 b4 = *(const float4*)&bias[q4];
        float rdeg = __builtin_amdgcn_rcpf(degv);
        float4 val;
        val.x = ftanh((acc.x + b4.x) * rdeg);
        val.y = ftanh((acc.y + b4.y) * rdeg);
        val.z = ftanh((acc.z + b4.z) * rdeg);
        val.w = ftanh((acc.w + b4.w) * rdeg);
        ushort4 hv4 = {f2bf(val.x), f2bf(val.y), f2bf(val.z), f2bf(val.w)};
        *(ushort4*)&hout[(size_t)d * 32 + q4] = hv4;
        float v = (val.x * w4.x + val.y * w4.y) + (val.z * w4.z + val.w * w4.w);
        v += __shfl_xor(v, 1, 8);
        v += __shfl_xor(v, 2, 8);
        v += __shfl_xor(v, 4, 8);
        if (q == 0) z4[d] = v;
    }
}

// ---------------------------------------------------------------------------
// Fused: layer-4 gather (z4 staged in LDS) -> h4; msg=[h1 h2 h3 h4];
// phi=relu(msg@phiW+b); per-graph partial sums -> one atomicAdd set per block.
__global__ __launch_bounds__(512) void k_phi(const float* __restrict__ degs,
                                             const int* __restrict__ ell,
                                             const float* __restrict__ z4,
                                             const float* __restrict__ b3,
                                             const bf16* __restrict__ h1,
                                             const bf16* __restrict__ h2,
                                             const bf16* __restrict__ h3,
                                             const float* __restrict__ phiW,
                                             const float* __restrict__ phib,
                                             float* __restrict__ summed) {
    __shared__ float pl[30 * 100];   // phiW transposed: pl[c][j]
    __shared__ float ml[16 * 100];   // msg rows (f32 in LDS)
    __shared__ float part[8][32];
    __shared__ float z4l[2048];      // graph z4 slice
    int tid = threadIdx.x;
    for (int i = tid; i < 30 * 97; i += 512) {
        int cc = i / 97, jj = i - cc * 97;
        pl[cc * 100 + jj] = phiW[jj * 30 + cc];
    }
    int blk = xcd_swz(blockIdx.x, 512);             // 4096 blocks -> chunk 512
    int r = tid >> 5, c = tid & 31;
    int d = blk * 16 + r;
    int g = d >> 11;
    const float* z4g = z4 + ((size_t)g << 11);
    for (int i = tid; i < 2048; i += 512) z4l[i] = z4g[i];
    __syncthreads();
    float degv = degs[d];
    int cnt = (int)degv - 1; if (cnt > MAXD) cnt = MAXD;
    const int* row = ell + (size_t)d * MAXD;
    float acc = 0.f;
    for (int j = c; j < cnt; j += 32) acc += z4l[row[j] & 2047];
    #pragma unroll
    for (int off = 16; off; off >>= 1) acc += __shfl_xor(acc, off, 32);
    float h4 = ftanh((acc + z4l[d & 2047] + b3[0]) * __builtin_amdgcn_rcpf(degv));
    ml[r * 100 + c]      = bf2f(h1[(size_t)d * 32 + c]);
    ml[r * 100 + 32 + c] = bf2f(h2[(size_t)d * 32 + c]);
    ml[r * 100 + 64 + c] = bf2f(h3[(size_t)d * 32 + c]);
    if (c == 0) ml[r * 100 + 96] = h4;
    __syncthreads();
    float s = 0.f;
    if (c < 30) {
        const float* mrow = ml + r * 100;
        const float* prow = pl + c * 100;
        float4 a4 = {0.f, 0.f, 0.f, 0.f};
        #pragma unroll
        for (int j = 0; j < 96; j += 4) {
            float4 mv = *(const float4*)&mrow[j];
            float4 pv = *(const float4*)&prow[j];
            a4.x += mv.x * pv.x; a4.y += mv.y * pv.y;
            a4.z += mv.z * pv.z; a4.w += mv.w * pv.w;
        }
        s = (a4.x + a4.y) + (a4.z + a4.w) + mrow[96] * prow[96] + phib[c];
        s = fmaxf(s, 0.f);
    }
    s += __shfl_down(s, 32);                 // node pair within each wave
    int wave = tid >> 6;
    if ((tid & 63) < 32) part[wave][tid & 31] = s;
    __syncthreads();
    if (tid < 32) {
        float tot = 0.f;
        #pragma unroll
        for (int w = 0; w < 8; ++w) tot += part[w][tid];
        if (tid < 30) atomicAdd(&summed[g * 30 + tid], tot);
    }
}

// ---------------------------------------------------------------------------
// out = summed @ rhoW + rhob   (32x30 @ 30x32)
__global__ __launch_bounds__(1024) void k_rho(const float* __restrict__ summed,
                                              const float* __restrict__ rhoW,
                                              const float* __restrict__ rhob,
                                              float* __restrict__ out) {
    int tid = threadIdx.x;
    int b = tid >> 5, o = tid & 31;
    float s = rhob[o];
    #pragma unroll
    for (int k = 0; k < 30; ++k) s += summed[b * 30 + k] * rhoW[k * 32 + o];
    out[tid] = s;
}

// ---------------------------------------------------------------------------
extern "C" void kernel_launch(void* const* d_in, const int* in_sizes, int n_in,
                              void* d_out, int out_size, void* d_ws, size_t ws_size,
                              hipStream_t stream) {
    const float* feat = (const float*)d_in[0];
    const float* degs = (const float*)d_in[1];
    const int*   ei   = (const int*)d_in[2];
    const float* W0   = (const float*)d_in[3];
    const float* b0   = (const float*)d_in[4];
    const float* W1   = (const float*)d_in[5];
    const float* b1   = (const float*)d_in[6];
    const float* W2   = (const float*)d_in[7];
    const float* b2   = (const float*)d_in[8];
    const float* W3   = (const float*)d_in[9];
    const float* b3   = (const float*)d_in[10];
    const float* phiW = (const float*)d_in[11];
    const float* phib = (const float*)d_in[12];
    const float* rhoW = (const float*)d_in[13];
    const float* rhob = (const float*)d_in[14];

    char* ws = (char*)d_ws;
    int*   cursor = (int*)(ws + WS_CURSOR);
    float* summed = (float*)(ws + WS_SUMMED);
    int*   ell    = (int*)(ws + WS_ELL);
    bf16*  za     = (bf16*)(ws + WS_ZA);
    bf16*  zb     = (bf16*)(ws + WS_ZB);
    bf16*  h1     = (bf16*)(ws + WS_H1);
    bf16*  h2     = (bf16*)(ws + WS_H2);
    bf16*  h3     = (bf16*)(ws + WS_H3);
    float* z4     = (float*)(ws + WS_Z4);
    float* out    = (float*)d_out;

    // zero cursor + summed (ws is poisoned to 0xAA before every launch)
    hipMemsetAsync(ws, 0, WS_SUMMED + NG * 30 * 4, stream);

    k_build <<<NE / 1024, 256, 0, stream>>>(ei, cursor, ell);
    k_gemm1 <<<NN / 64, 256, 0, stream>>>(feat, W0, za);
    k_layer <<<NN / 256, 1024, 0, stream>>>(degs, ell, za, b0, W1, h1, zb);
    k_layer <<<NN / 256, 1024, 0, stream>>>(degs, ell, zb, b1, W2, h2, za);
    k_layer3<<<NN / 256, 1024, 0, stream>>>(degs, ell, za, b2, W3, h3, z4);
    k_phi   <<<NN / 16, 512, 0, stream>>>(degs, ell, z4, b3, h1, h2, h3, phiW, phib, summed);
    k_rho   <<<1, 1024, 0, stream>>>(summed, rhoW, rhob, out);
}

// Round 13
// 215.442 us; speedup vs baseline: 1.4475x; 1.4475x over previous
//
#include <hip/hip_runtime.h>
#include <hip/hip_bf16.h>

// Problem constants (fixed by the reference harness)
#define NN 65536            // total nodes
#define NE (NN * 16)        // total edges = 1,048,576
#define NG 32               // graphs
#define MAXD 64             // ELL slots per node (max in-degree ~45 for Poisson(16))

// Workspace layout (bytes).  z/h buffers are bf16 (2B), z4 is f32.
#define WS_CURSOR 0                         // (unused now)
#define WS_SUMMED 262144                    // NG*30 f32
#define WS_ELL    1048576                   // int ELL: NN*64*4 = 16 MB
#define WS_ZA     (WS_ELL + NN * MAXD * 4)  // NN*32 bf16 = 4 MB
#define WS_ZB     (WS_ZA + NN * 32 * 2)
#define WS_H1     (WS_ZB + NN * 32 * 2)
#define WS_H2     (WS_H1 + NN * 32 * 2)
#define WS_H3     (WS_H2 + NN * 32 * 2)
#define WS_Z4     (WS_H3 + NN * 32 * 2)     // NN f32

typedef unsigned short bf16;

// XCD-affine swizzle: 8 XCDs, round-robin dispatch (blockIdx % 8).
__device__ __forceinline__ int xcd_swz(int b, int chunk) {
    return (b & 7) * chunk + (b >> 3);
}

__device__ __forceinline__ float ftanh(float x) {
    float xc = fmaxf(fminf(x, 15.f), -15.f);
    float e = __expf(2.f * xc);
    return (e - 1.f) * __builtin_amdgcn_rcpf(e + 1.f);
}

__device__ __forceinline__ float bf2f(bf16 u) {
    return __uint_as_float(((unsigned int)u) << 16);
}
__device__ __forceinline__ bf16 f2bf(float x) {
    unsigned int b = __float_as_uint(x);
    b += 0x7FFF + ((b >> 16) & 1);          // round to nearest even
    return (bf16)(b >> 16);
}

// ---------------------------------------------------------------------------
// LDS-atomic ELL build.  512 blocks = 32 graphs x 16 dst-ranges (128 nodes).
// Block scans its graph's whole edge slice (coalesced, L2-resident after the
// first sub-block touches it), filters dst in range, LDS-atomic slot, then a
// fire-and-forget global store (no L2 atomic round-trip in the chain).
#define BB_SUB 16
#define BB_RANGE (2048 / BB_SUB)            // 128 dst nodes per block

__global__ __launch_bounds__(1024) void k_build(const int* __restrict__ ei,
                                                int* __restrict__ ell) {
    __shared__ int lcnt[BB_RANGE];
    int tid = threadIdx.x;
    int blk = xcd_swz(blockIdx.x, 64);      // 512 blocks -> chunk 64
    int g = blk >> 4, sub = blk & 15;
    int dbase = (g << 11) + sub * BB_RANGE;
    if (tid < BB_RANGE) lcnt[tid] = 0;
    __syncthreads();
    const int4* s4 = (const int4*)ei + ((size_t)g << 13);        // g*32768/4
    const int4* d4 = (const int4*)(ei + NE) + ((size_t)g << 13);
    #pragma unroll
    for (int it = 0; it < 8; ++it) {
        int i = it * 1024 + tid;
        int4 s = s4[i];
        int4 d = d4[i];
        int r, t;
        r = d.x - dbase; if ((unsigned)r < BB_RANGE) { t = atomicAdd(&lcnt[r], 1); if (t < MAXD) ell[d.x * MAXD + t] = s.x; }
        r = d.y - dbase; if ((unsigned)r < BB_RANGE) { t = atomicAdd(&lcnt[r], 1); if (t < MAXD) ell[d.y * MAXD + t] = s.y; }
        r = d.z - dbase; if ((unsigned)r < BB_RANGE) { t = atomicAdd(&lcnt[r], 1); if (t < MAXD) ell[d.z * MAXD + t] = s.z; }
        r = d.w - dbase; if ((unsigned)r < BB_RANGE) { t = atomicAdd(&lcnt[r], 1); if (t < MAXD) ell[d.w * MAXD + t] = s.w; }
    }
}

// ---------------------------------------------------------------------------
// z1 = feat (N x 128) @ W0 (128 x 32), output bf16.
__global__ __launch_bounds__(256) void k_gemm1(const float* __restrict__ feat,
                                               const float* __restrict__ W0,
                                               bf16* __restrict__ z1) {
    __shared__ float wl[32 * 132];
    __shared__ float hl[64 * 132];
    int tid = threadIdx.x;
    for (int i = tid; i < 128 * 32; i += 256) {
        int k = i >> 5, c = i & 31;
        wl[c * 132 + k] = W0[i];
    }
    int base = blockIdx.x * 64;
    const float* fsrc = feat + (size_t)base * 128;
    #pragma unroll
    for (int v = 0; v < 8; ++v) {
        int flat = v * 1024 + tid * 4;
        int rr = flat >> 7, kk = flat & 127;
        *(float4*)&hl[rr * 132 + kk] = *(const float4*)&fsrc[flat];
    }
    __syncthreads();
    int cg = tid & 15, rg = tid >> 4;
    int c0 = cg * 2, r0 = rg * 4;
    float acc[4][2] = {};
    #pragma unroll 2
    for (int k = 0; k < 128; k += 4) {
        float4 wa = *(const float4*)&wl[c0 * 132 + k];
        float4 wb = *(const float4*)&wl[(c0 + 1) * 132 + k];
        #pragma unroll
        for (int rr = 0; rr < 4; ++rr) {
            float4 hv = *(const float4*)&hl[(r0 + rr) * 132 + k];
            acc[rr][0] += hv.x * wa.x + hv.y * wa.y + hv.z * wa.z + hv.w * wa.w;
            acc[rr][1] += hv.x * wb.x + hv.y * wb.y + hv.z * wb.z + hv.w * wb.w;
        }
    }
    #pragma unroll
    for (int rr = 0; rr < 4; ++rr) {
        int d = base + r0 + rr;
        unsigned int pk = (unsigned int)f2bf(acc[rr][0]) |
                          ((unsigned int)f2bf(acc[rr][1]) << 16);
        *(unsigned int*)&z1[(size_t)d * 32 + c0] = pk;
    }
}

// ---------------------------------------------------------------------------
// bf16 gather via L2: 8-lane node group, lane q handles cols 4q..4q+3.
// One neighbor row = 64B = ONE cache line (8 lanes x 8B ushort4).
#define GB8(iv) do {                                                           \
    int s0=__shfl((iv),0,8), s1=__shfl((iv),1,8), s2=__shfl((iv),2,8), s3=__shfl((iv),3,8); \
    int s4=__shfl((iv),4,8), s5=__shfl((iv),5,8), s6=__shfl((iv),6,8), s7=__shfl((iv),7,8); \
    ushort4 v0=*(const ushort4*)&zin[(size_t)s0*32+q4];                        \
    ushort4 v1=*(const ushort4*)&zin[(size_t)s1*32+q4];                        \
    ushort4 v2=*(const ushort4*)&zin[(size_t)s2*32+q4];                        \
    ushort4 v3=*(const ushort4*)&zin[(size_t)s3*32+q4];                        \
    ushort4 v4=*(const ushort4*)&zin[(size_t)s4*32+q4];                        \
    ushort4 v5=*(const ushort4*)&zin[(size_t)s5*32+q4];                        \
    ushort4 v6=*(const ushort4*)&zin[(size_t)s6*32+q4];                        \
    ushort4 v7=*(const ushort4*)&zin[(size_t)s7*32+q4];                        \
    acc.x += ((bf2f(v0.x)+bf2f(v1.x))+(bf2f(v2.x)+bf2f(v3.x)))                 \
           + ((bf2f(v4.x)+bf2f(v5.x))+(bf2f(v6.x)+bf2f(v7.x)));                \
    acc.y += ((bf2f(v0.y)+bf2f(v1.y))+(bf2f(v2.y)+bf2f(v3.y)))                 \
           + ((bf2f(v4.y)+bf2f(v5.y))+(bf2f(v6.y)+bf2f(v7.y)));                \
    acc.z += ((bf2f(v0.z)+bf2f(v1.z))+(bf2f(v2.z)+bf2f(v3.z)))                 \
           + ((bf2f(v4.z)+bf2f(v5.z))+(bf2f(v6.z)+bf2f(v7.z)));                \
    acc.w += ((bf2f(v0.w)+bf2f(v1.w))+(bf2f(v2.w)+bf2f(v3.w)))                 \
           + ((bf2f(v4.w)+bf2f(v5.w))+(bf2f(v6.w)+bf2f(v7.w)));                \
} while (0)

__device__ __forceinline__ float4 gatherbf(const int* __restrict__ row, int cnt,
                                           const bf16* __restrict__ zin,
                                           int q4, float4 acc) {
    int q = q4 >> 2;
    int i0 = row[q], i1 = row[8 + q], i2 = row[16 + q], i3 = row[24 + q];
    int m = cnt < 32 ? cnt : 32;
    if (m >= 8)  GB8(i0);
    if (m >= 16) GB8(i1);
    if (m >= 24) GB8(i2);
    if (m >= 32) GB8(i3);
    int done = m & ~7;
    if (done < m) {
        int ivr = (done == 0) ? i0 : (done == 8) ? i1 : (done == 16) ? i2 : i3;
        for (int j = done; j < m; ++j) {
            int s = __shfl(ivr, j - done, 8);
            ushort4 v = *(const ushort4*)&zin[(size_t)s * 32 + q4];
            acc.x += bf2f(v.x); acc.y += bf2f(v.y);
            acc.z += bf2f(v.z); acc.w += bf2f(v.w);
        }
    }
    for (int j = 32; j < cnt && j < MAXD; ++j) {     // astronomically rare
        int s = row[j];
        ushort4 v = *(const ushort4*)&zin[(size_t)s * 32 + q4];
        acc.x += bf2f(v.x); acc.y += bf2f(v.y);
        acc.z += bf2f(v.z); acc.w += bf2f(v.w);
    }
    return acc;
}

// ---------------------------------------------------------------------------
// Fused: agg = A*zin (+self); h = ftanh((agg+b)/deg); znext = h @ Wn (32x32).
// 32 nodes/block, node = 8 lanes.  All node vectors bf16.
__global__ __launch_bounds__(256) void k_layer(const float* __restrict__ degs,
                                               const int* __restrict__ ell,
                                               const bf16* __restrict__ zin,
                                               const float* __restrict__ bias,
                                               const float* __restrict__ Wn,
                                               bf16* __restrict__ hout,
                                               bf16* __restrict__ znext) {
    __shared__ float wt[32 * 36];    // W transposed: wt[c][k]
    __shared__ float hl[32 * 36];
    int tid = threadIdx.x;
    for (int i = tid; i < 1024; i += 256) {
        int k = i >> 5, c = i & 31;
        wt[c * 36 + k] = Wn[i];
    }
    int blk = xcd_swz(blockIdx.x, 256);             // 2048 blocks -> chunk 256
    int r = tid >> 3, q4 = (tid & 7) * 4;
    int d = blk * 32 + r;
    float degv = degs[d];
    int cnt = (int)degv - 1;
    const int* row = ell + (size_t)d * MAXD;
    ushort4 sv = *(const ushort4*)&zin[(size_t)d * 32 + q4];   // self term
    float4 acc = {bf2f(sv.x), bf2f(sv.y), bf2f(sv.z), bf2f(sv.w)};
    acc = gatherbf(row, cnt, zin, q4, acc);
    float4 b4 = *(const float4*)&bias[q4];
    float rdeg = __builtin_amdgcn_rcpf(degv);
    float4 val;
    val.x = ftanh((acc.x + b4.x) * rdeg);
    val.y = ftanh((acc.y + b4.y) * rdeg);
    val.z = ftanh((acc.z + b4.z) * rdeg);
    val.w = ftanh((acc.w + b4.w) * rdeg);
    ushort4 hv4 = {f2bf(val.x), f2bf(val.y), f2bf(val.z), f2bf(val.w)};
    *(ushort4*)&hout[(size_t)d * 32 + q4] = hv4;
    *(float4*)&hl[r * 36 + q4] = val;
    __syncthreads();
    #pragma unroll
    for (int it = 0; it < 4; ++it) {
        int wid = tid + it * 256;
        int n = wid >> 5, c = wid & 31;
        const float* hrow = &hl[n * 36];
        const float* wrow = &wt[c * 36];
        float4 a4 = {0.f, 0.f, 0.f, 0.f};
        #pragma unroll
        for (int k = 0; k < 32; k += 4) {
            float4 hv = *(const float4*)&hrow[k];
            float4 wv = *(const float4*)&wrow[k];
            a4.x += hv.x * wv.x; a4.y += hv.y * wv.y;
            a4.z += hv.z * wv.z; a4.w += hv.w * wv.w;
        }
        znext[(size_t)(blk * 32 + n) * 32 + c] =
            f2bf((a4.x + a4.y) + (a4.z + a4.w));
    }
}

// ---------------------------------------------------------------------------
// Layer-3 variant: z4 = h3 @ W3 is 1-wide (f32) -> in-group reduce.
__global__ __launch_bounds__(256) void k_layer3(const float* __restrict__ degs,
                                                const int* __restrict__ ell,
                                                const bf16* __restrict__ zin,
                                                const float* __restrict__ bias,
                                                const float* __restrict__ W3,
                                                bf16* __restrict__ hout,
                                                float* __restrict__ z4) {
    int tid = threadIdx.x;
    int blk = xcd_swz(blockIdx.x, 256);
    int r = tid >> 3, q4 = (tid & 7) * 4;
    int d = blk * 32 + r;
    float degv = degs[d];
    int cnt = (int)degv - 1;
    const int* row = ell + (size_t)d * MAXD;
    ushort4 sv = *(const ushort4*)&zin[(size_t)d * 32 + q4];
    float4 acc = {bf2f(sv.x), bf2f(sv.y), bf2f(sv.z), bf2f(sv.w)};
    acc = gatherbf(row, cnt, zin, q4, acc);
    float4 b4 = *(const float4*)&bias[q4];
    float rdeg = __builtin_amdgcn_rcpf(degv);
    float4 val;
    val.x = ftanh((acc.x + b4.x) * rdeg);
    val.y = ftanh((acc.y + b4.y) * rdeg);
    val.z = ftanh((acc.z + b4.z) * rdeg);
    val.w = ftanh((acc.w + b4.w) * rdeg);
    ushort4 hv4 = {f2bf(val.x), f2bf(val.y), f2bf(val.z), f2bf(val.w)};
    *(ushort4*)&hout[(size_t)d * 32 + q4] = hv4;
    float4 w4 = *(const float4*)&W3[q4];
    float v = (val.x * w4.x + val.y * w4.y) + (val.z * w4.z + val.w * w4.w);
    v += __shfl_xor(v, 1, 8);
    v += __shfl_xor(v, 2, 8);
    v += __shfl_xor(v, 4, 8);
    if ((tid & 7) == 0) z4[d] = v;
}

// ---------------------------------------------------------------------------
// Fused: layer-4 gather (1-wide f32, direct L2) -> h4; msg=[h1 h2 h3 h4];
// phi=relu(msg@phiW+b); per-graph partial sum -> one atomicAdd set per block.
__global__ __launch_bounds__(512) void k_phi(const float* __restrict__ degs,
                                             const int* __restrict__ ell,
                                             const float* __restrict__ z4,
                                             const float* __restrict__ b3,
                                             const bf16* __restrict__ h1,
                                             const bf16* __restrict__ h2,
                                             const bf16* __restrict__ h3,
                                             const float* __restrict__ phiW,
                                             const float* __restrict__ phib,
                                             float* __restrict__ summed) {
    __shared__ float pl[30 * 100];   // phiW transposed: pl[c][j]
    __shared__ float ml[16 * 100];   // msg rows (f32 in LDS)
    __shared__ float part[8][32];
    int tid = threadIdx.x;
    for (int i = tid; i < 30 * 97; i += 512) {
        int cc = i / 97, jj = i - cc * 97;
        pl[cc * 100 + jj] = phiW[jj * 30 + cc];
    }
    int blk = xcd_swz(blockIdx.x, 512);             // 4096 blocks -> chunk 512
    int r = tid >> 5, c = tid & 31;
    int d = blk * 16 + r;
    int g = d >> 11;
    float degv = degs[d];
    int cnt = (int)degv - 1; if (cnt > MAXD) cnt = MAXD;
    const int* row = ell + (size_t)d * MAXD;
    float acc = 0.f;
    for (int j = c; j < cnt; j += 32) acc += z4[row[j]];
    #pragma unroll
    for (int off = 16; off; off >>= 1) acc += __shfl_xor(acc, off, 32);
    float h4 = ftanh((acc + z4[d] + b3[0]) * __builtin_amdgcn_rcpf(degv));
    ml[r * 100 + c]      = bf2f(h1[(size_t)d * 32 + c]);
    ml[r * 100 + 32 + c] = bf2f(h2[(size_t)d * 32 + c]);
    ml[r * 100 + 64 + c] = bf2f(h3[(size_t)d * 32 + c]);
    if (c == 0) ml[r * 100 + 96] = h4;
    __syncthreads();
    float s = 0.f;
    if (c < 30) {
        const float* mrow = ml + r * 100;
        const float* prow = pl + c * 100;
        float4 a4 = {0.f, 0.f, 0.f, 0.f};
        #pragma unroll
        for (int j = 0; j < 96; j += 4) {
            float4 mv = *(const float4*)&mrow[j];
            float4 pv = *(const float4*)&prow[j];
            a4.x += mv.x * pv.x; a4.y += mv.y * pv.y;
            a4.z += mv.z * pv.z; a4.w += mv.w * pv.w;
        }
        s = (a4.x + a4.y) + (a4.z + a4.w) + mrow[96] * prow[96] + phib[c];
        s = fmaxf(s, 0.f);
    }
    s += __shfl_down(s, 32);                 // node pair within each wave
    int wave = tid >> 6;
    if ((tid & 63) < 32) part[wave][tid & 31] = s;
    __syncthreads();
    if (tid < 32) {
        float tot = 0.f;
        #pragma unroll
        for (int w = 0; w < 8; ++w) tot += part[w][tid];
        if (tid < 30) atomicAdd(&summed[g * 30 + tid], tot);
    }
}

// ---------------------------------------------------------------------------
// out = summed @ rhoW + rhob   (32x30 @ 30x32)
__global__ __launch_bounds__(1024) void k_rho(const float* __restrict__ summed,
                                              const float* __restrict__ rhoW,
                                              const float* __restrict__ rhob,
                                              float* __restrict__ out) {
    int tid = threadIdx.x;
    int b = tid >> 5, o = tid & 31;
    float s = rhob[o];
    #pragma unroll
    for (int k = 0; k < 30; ++k) s += summed[b * 30 + k] * rhoW[k * 32 + o];
    out[tid] = s;
}

// ---------------------------------------------------------------------------
extern "C" void kernel_launch(void* const* d_in, const int* in_sizes, int n_in,
                              void* d_out, int out_size, void* d_ws, size_t ws_size,
                              hipStream_t stream) {
    const float* feat = (const float*)d_in[0];
    const float* degs = (const float*)d_in[1];
    const int*   ei   = (const int*)d_in[2];
    const float* W0   = (const float*)d_in[3];
    const float* b0   = (const float*)d_in[4];
    const float* W1   = (const float*)d_in[5];
    const float* b1   = (const float*)d_in[6];
    const float* W2   = (const float*)d_in[7];
    const float* b2   = (const float*)d_in[8];
    const float* W3   = (const float*)d_in[9];
    const float* b3   = (const float*)d_in[10];
    const float* phiW = (const float*)d_in[11];
    const float* phib = (const float*)d_in[12];
    const float* rhoW = (const float*)d_in[13];
    const float* rhob = (const float*)d_in[14];

    char* ws = (char*)d_ws;
    float* summed = (float*)(ws + WS_SUMMED);
    int*   ell    = (int*)(ws + WS_ELL);
    bf16*  za     = (bf16*)(ws + WS_ZA);
    bf16*  zb     = (bf16*)(ws + WS_ZB);
    bf16*  h1     = (bf16*)(ws + WS_H1);
    bf16*  h2     = (bf16*)(ws + WS_H2);
    bf16*  h3     = (bf16*)(ws + WS_H3);
    float* z4     = (float*)(ws + WS_Z4);
    float* out    = (float*)d_out;

    // zero summed only (LDS-atomic build needs no global cursor)
    hipMemsetAsync(ws + WS_SUMMED, 0, NG * 30 * 4, stream);

    k_build <<<512, 1024, 0, stream>>>(ei, ell);
    k_gemm1 <<<NN / 64, 256, 0, stream>>>(feat, W0, za);
    k_layer <<<NN / 32, 256, 0, stream>>>(degs, ell, za, b0, W1, h1, zb);
    k_layer <<<NN / 32, 256, 0, stream>>>(degs, ell, zb, b1, W2, h2, za);
    k_layer3<<<NN / 32, 256, 0, stream>>>(degs, ell, za, b2, W3, h3, z4);
    k_phi   <<<NN / 16, 512, 0, stream>>>(degs, ell, z4, b3, h1, h2, h3, phiW, phib, summed);
    k_rho   <<<1, 1024, 0, stream>>>(summed, rhoW, rhob, out);
}